// Round 3
// baseline (470.300 us; speedup 1.0000x reference)
//
#include <hip/hip_runtime.h>
#include <cmath>
#include <math.h>

namespace {

constexpr int Bn = 4;
constexpr int Cn = 64;
constexpr int Wn = 64;
constexpr int Hn = 1024;
constexpr int HWn = Wn * Hn;      // 65536
constexpr int CHWn = Cn * HWn;    // 4194304

struct ShiftConsts { float m[27]; };  // m0[9] | m1[9] | m2[9]

typedef float f32x4 __attribute__((ext_vector_type(4)));
typedef short bf16x8 __attribute__((ext_vector_type(8)));
union Frag { uint4 u; bf16x8 s; };

__device__ inline unsigned bf16rne(float f) {
  unsigned u = __float_as_uint(f);
  return (u + 0x7FFFu + ((u >> 16) & 1u)) >> 16;
}
__device__ inline unsigned packbf(float a, float b) {
  return bf16rne(a) | (bf16rne(b) << 16);
}
__device__ inline float bflo(unsigned d) { return __uint_as_float(d << 16); }
__device__ inline float bfhi(unsigned d) { return __uint_as_float(d & 0xFFFF0000u); }

// ---------------- GroupNorm stats, stage 1: partial sums (atomic) ----------------
__global__ __launch_bounds__(256) void gn_partial_kernel(
    const float* __restrict__ x, float* __restrict__ partial) {
  const int bg = blockIdx.x >> 4, part = blockIdx.x & 15;
  const float4* base = (const float4*)(x + (size_t)bg * 2 * HWn) + part * 2048;
  float s = 0.f, s2 = 0.f;
  for (int i = threadIdx.x; i < 2048; i += 256) {
    const float4 v = base[i];
    s += v.x + v.y + v.z + v.w;
    s2 += v.x * v.x + v.y * v.y + v.z * v.z + v.w * v.w;
  }
  #pragma unroll
  for (int off = 32; off > 0; off >>= 1) {
    s  += __shfl_down(s, off, 64);
    s2 += __shfl_down(s2, off, 64);
  }
  __shared__ float red[8];
  const int wid = threadIdx.x >> 6, lid = threadIdx.x & 63;
  if (lid == 0) { red[wid * 2] = s; red[wid * 2 + 1] = s2; }
  __syncthreads();
  if (threadIdx.x == 0) {
    float ts = red[0] + red[2] + red[4] + red[6];
    float t2 = red[1] + red[3] + red[5] + red[7];
    atomicAdd(&partial[bg * 2], ts);
    atomicAdd(&partial[bg * 2 + 1], t2);
  }
}

// ---------------- GroupNorm stats, stage 2: finalize ----------------
__global__ void gn_final_kernel(const float* __restrict__ partial,
                                float* __restrict__ stats) {
  const int i = threadIdx.x;
  if (i < 128) {
    const float inv = 1.0f / (2.0f * HWn);
    const float mean = partial[2 * i] * inv;
    const float var = partial[2 * i + 1] * inv - mean * mean;
    stats[2 * i] = mean;
    stats[2 * i + 1] = rsqrtf(var + 1e-6f);
  }
}

// ------- Dual GEMM (MFMA): Y = W_a @ relu(gn(x)), Z = W_b @ relu(gn(x)) + b1 -------
// Block = 128 j x 64 o. Output layout NHWC bf16: Y[((b*64+w)*1024+h)*64 + k]
__global__ __launch_bounds__(256, 2) void dual_gemm_kernel(
    const float* __restrict__ x, const float* __restrict__ stats,
    const float* __restrict__ gw, const float* __restrict__ gb,
    const float* __restrict__ w1, const float* __restrict__ b1,
    ushort* __restrict__ Y, ushort* __restrict__ Z) {
  __shared__ float2 scsh[64];
  __shared__ float bias[64];
  __shared__ __align__(16) ushort dsY[128 * 72];
  __shared__ __align__(16) ushort dsZ[128 * 72];
  const int blk = blockIdx.x;
  const int h0 = (blk & 7) * 128;
  const int w  = (blk >> 3) & 63;
  const int b  = blk >> 9;
  const int t  = threadIdx.x;
  const int lane = t & 63, wv = t >> 6;
  const int n = lane & 15, q = lane >> 4;

  if (t < 64) {
    const int g = t >> 1;
    const float mean = stats[(b * 32 + g) * 2];
    const float rstd = stats[(b * 32 + g) * 2 + 1];
    const float sc = rstd * gw[t];
    scsh[t] = make_float2(sc, gb[t] - mean * sc);
    bias[t] = b1[t];
  }
  __syncthreads();

  // B fragments: tile0 -> j = jg0, tile1 -> j = jg0+1 (even/odd interleave)
  const int jg0 = h0 + wv * 32 + 2 * n;
  const float* xb = x + (size_t)b * CHWn + (size_t)w * Hn;
  Frag Bf[2][2];  // [kh][tile]
  #pragma unroll
  for (int kh = 0; kh < 2; kh++) {
    unsigned d0[4], d1[4];
    #pragma unroll
    for (int p = 0; p < 4; p++) {
      const int c0 = kh * 32 + q * 8 + p * 2;
      const float2 s0 = scsh[c0], s1 = scsh[c0 + 1];
      const float2 xa = *(const float2*)&xb[(size_t)c0 * HWn + jg0];
      const float2 xc = *(const float2*)&xb[(size_t)(c0 + 1) * HWn + jg0];
      const float v00 = fmaxf(xa.x * s0.x + s0.y, 0.f);  // c0,   j0
      const float v01 = fmaxf(xa.y * s0.x + s0.y, 0.f);  // c0,   j1
      const float v10 = fmaxf(xc.x * s1.x + s1.y, 0.f);  // c0+1, j0
      const float v11 = fmaxf(xc.y * s1.x + s1.y, 0.f);  // c0+1, j1
      d0[p] = packbf(v00, v10);
      d1[p] = packbf(v01, v11);
    }
    Bf[kh][0].u = make_uint4(d0[0], d0[1], d0[2], d0[3]);
    Bf[kh][1].u = make_uint4(d1[0], d1[1], d1[2], d1[3]);
  }

  f32x4 accY[4][2], accZ[4][2];
  #pragma unroll
  for (int os = 0; os < 4; os++)
    #pragma unroll
    for (int tl = 0; tl < 2; tl++) { accY[os][tl] = (f32x4)0.f; accZ[os][tl] = (f32x4)0.f; }

  #pragma unroll
  for (int os = 0; os < 4; os++) {
    const int o = os * 16 + n;
    #pragma unroll
    for (int kh = 0; kh < 2; kh++) {
      const int k = kh * 32 + q * 8;
      const float* wra = w1 + o * 131 + k;
      const float* wrb = w1 + o * 131 + 64 + k;
      Frag fa, fb;
      unsigned da[4], db[4];
      #pragma unroll
      for (int p = 0; p < 4; p++) {
        da[p] = packbf(wra[2 * p], wra[2 * p + 1]);
        db[p] = packbf(wrb[2 * p], wrb[2 * p + 1]);
      }
      fa.u = make_uint4(da[0], da[1], da[2], da[3]);
      fb.u = make_uint4(db[0], db[1], db[2], db[3]);
      #pragma unroll
      for (int tl = 0; tl < 2; tl++) {
        accY[os][tl] = __builtin_amdgcn_mfma_f32_16x16x32_bf16(fa.s, Bf[kh][tl].s, accY[os][tl], 0, 0, 0);
        accZ[os][tl] = __builtin_amdgcn_mfma_f32_16x16x32_bf16(fb.s, Bf[kh][tl].s, accZ[os][tl], 0, 0, 0);
      }
    }
  }

  // D -> LDS repack: ds[j][o] (stride 72)
  #pragma unroll
  for (int os = 0; os < 4; os++) {
    #pragma unroll
    for (int tl = 0; tl < 2; tl++) {
      const int jrow = wv * 32 + 2 * n + tl;
      #pragma unroll
      for (int rp = 0; rp < 4; rp += 2) {
        const int o = os * 16 + q * 4 + rp;
        *(unsigned*)&dsY[jrow * 72 + o] = packbf(accY[os][tl][rp], accY[os][tl][rp + 1]);
        *(unsigned*)&dsZ[jrow * 72 + o] =
            packbf(accZ[os][tl][rp] + bias[o], accZ[os][tl][rp + 1] + bias[o + 1]);
      }
    }
  }
  __syncthreads();

  #pragma unroll
  for (int p = 0; p < 4; p++) {
    const int slot = t + 256 * p;
    const int j = slot >> 3, og = slot & 7;
    const size_t gidx = (((size_t)b * Wn + w) * Hn + h0 + j) * 64 + og * 8;
    *(uint4*)&Y[gidx] = *(const uint4*)&dsY[j * 72 + og * 8];
    *(uint4*)&Z[gidx] = *(const uint4*)&dsZ[j * 72 + og * 8];
  }
}

// ---- 9-shift fused MFMA: out = max_s( W2 @ relu(Y_s + Z + pe_s) ) + b2 (+ x) ----
// Register-direct B-fragment build: no h1 LDS round trip, no inner-loop barriers.
__global__ __launch_bounds__(256, 3) void shift_max_kernel(
    const ushort* __restrict__ Y, const ushort* __restrict__ Z,
    const float* __restrict__ r, const float* __restrict__ w1,
    const float* __restrict__ w2, const float* __restrict__ b2,
    const float* __restrict__ xres, const int add_res,
    float* __restrict__ out, const ShiftConsts sc,
    float* __restrict__ partial) {
  __shared__ __align__(16) ushort ys[66 * 72];  // [jj][k], jj = h0-1 .. h0+64
  __shared__ __align__(16) float vst[9 * 64];   // vs table per shift
  __shared__ float rsh[3][68];
  __shared__ float gsA[32], gsB[32];
  const int blk = blockIdx.x;
  const int h0 = (blk & 15) * 64;
  const int w  = (blk >> 4) & 63;
  const int b  = blk >> 10;
  const int t  = threadIdx.x;
  const int lane = t & 63, wv = t >> 6;
  const int n = lane & 15, q = lane >> 4;
  const int jl = wv * 16 + n;  // this lane's B column (local j)

  // w2 A-fragments, resident all kernel
  Frag A[8];  // [os][kh]
  #pragma unroll
  for (int os = 0; os < 4; os++) {
    const int o = os * 16 + n;
    #pragma unroll
    for (int kh = 0; kh < 2; kh++) {
      const float4 f0 = *(const float4*)&w2[o * 64 + kh * 32 + q * 8];
      const float4 f1 = *(const float4*)&w2[o * 64 + kh * 32 + q * 8 + 4];
      A[os * 2 + kh].u = make_uint4(packbf(f0.x, f0.y), packbf(f0.z, f0.w),
                                    packbf(f1.x, f1.y), packbf(f1.z, f1.w));
    }
  }

  // zc[i] = z[jl][k_i] - rc*pw0[k_i], fp32 regs. k_i: i<8 -> q*8+i, i>=8 -> 32+q*8+(i-8)
  float zc[16];
  {
    const float rc = r[(size_t)b * HWn + (size_t)w * Hn + h0 + jl];
    const size_t zrow = (((size_t)b * Wn + w) * Hn + h0 + jl) * 64;
    const uint4 z0 = *(const uint4*)&Z[zrow + q * 8];
    const uint4 z1 = *(const uint4*)&Z[zrow + 32 + q * 8];
    const unsigned zw0[4] = {z0.x, z0.y, z0.z, z0.w};
    const unsigned zw1[4] = {z1.x, z1.y, z1.z, z1.w};
    #pragma unroll
    for (int p = 0; p < 4; p++) {
      const int ka = q * 8 + 2 * p, kb = 32 + q * 8 + 2 * p;
      zc[2 * p]     = bflo(zw0[p]) - rc * w1[ka * 131 + 128];
      zc[2 * p + 1] = bfhi(zw0[p]) - rc * w1[(ka + 1) * 131 + 128];
      zc[8 + 2 * p]     = bflo(zw1[p]) - rc * w1[kb * 131 + 128];
      zc[8 + 2 * p + 1] = bfhi(zw1[p]) - rc * w1[(kb + 1) * 131 + 128];
    }
  }

  // vs table: vst[s][k] = m0*pw0 + m1*pw1 + m2*pw2
  if (t < 64) {
    const float p0 = w1[t * 131 + 128];
    const float p1 = w1[t * 131 + 129];
    const float p2 = w1[t * 131 + 130];
    #pragma unroll
    for (int s = 0; s < 9; s++)
      vst[s * 64 + t] = sc.m[s] * p0 + sc.m[9 + s] * p1 + sc.m[18 + s] * p2;
  }
  if (t < 32) { gsA[t] = 0.f; gsB[t] = 0.f; }
  // r halo
  for (int i = t; i < 3 * 66; i += 256) {
    const int wi = i / 66, jj = i - wi * 66;
    const int wsrc = (w + wi - 1 + 64) & 63;
    const int hsrc = (h0 + jj - 1 + 1024) & 1023;
    rsh[wi][jj] = r[(size_t)b * HWn + wsrc * Hn + hsrc];
  }

  f32x4 om[4];
  #pragma unroll
  for (int os = 0; os < 4; os++) om[os] = (f32x4)(-INFINITY);

  for (int sw = -1; sw <= 1; sw++) {
    const int wsrc = (w - sw + 64) & 63;
    __syncthreads();  // previous ys readers done; also covers vst/rsh/gs init on first pass
    #pragma unroll
    for (int p = 0; p < 3; p++) {
      const int slot = t + 256 * p;
      if (slot < 66 * 8) {
        const int jj = slot >> 3, kg2 = slot & 7;
        const int hsrc = (h0 + jj - 1 + 1024) & 1023;
        *(uint4*)&ys[jj * 72 + kg2 * 8] =
            *(const uint4*)&Y[(((size_t)b * Wn + wsrc) * Hn + hsrc) * 64 + kg2 * 8];
      }
    }
    __syncthreads();
    #pragma unroll
    for (int sh = -1; sh <= 1; sh++) {
      const int s = (sw + 1) * 3 + (sh + 1);
      const float rsv = rsh[1 - sw][jl - sh + 1];
      const float* vsp = &vst[s * 64];
      const float4 va = *(const float4*)&vsp[q * 8];
      const float4 vb = *(const float4*)&vsp[q * 8 + 4];
      const float4 vc = *(const float4*)&vsp[32 + q * 8];
      const float4 vd = *(const float4*)&vsp[32 + q * 8 + 4];
      const float vs[16] = {va.x, va.y, va.z, va.w, vb.x, vb.y, vb.z, vb.w,
                            vc.x, vc.y, vc.z, vc.w, vd.x, vd.y, vd.z, vd.w};
      const int yrow = (jl - sh + 1) * 72;
      const uint4 ya = *(const uint4*)&ys[yrow + q * 8];
      const uint4 yb = *(const uint4*)&ys[yrow + 32 + q * 8];
      const unsigned yw0[4] = {ya.x, ya.y, ya.z, ya.w};
      const unsigned yw1[4] = {yb.x, yb.y, yb.z, yb.w};
      Frag Bf0, Bf1;
      unsigned h0w[4], h1w[4];
      #pragma unroll
      for (int p = 0; p < 4; p++) {
        const float a0 = fmaxf(bflo(yw0[p]) + zc[2 * p]     + rsv * vs[2 * p], 0.f);
        const float a1 = fmaxf(bfhi(yw0[p]) + zc[2 * p + 1] + rsv * vs[2 * p + 1], 0.f);
        const float b0 = fmaxf(bflo(yw1[p]) + zc[8 + 2 * p]     + rsv * vs[8 + 2 * p], 0.f);
        const float b1v = fmaxf(bfhi(yw1[p]) + zc[8 + 2 * p + 1] + rsv * vs[8 + 2 * p + 1], 0.f);
        h0w[p] = packbf(a0, a1);
        h1w[p] = packbf(b0, b1v);
      }
      Bf0.u = make_uint4(h0w[0], h0w[1], h0w[2], h0w[3]);
      Bf1.u = make_uint4(h1w[0], h1w[1], h1w[2], h1w[3]);
      #pragma unroll
      for (int os = 0; os < 4; os++) {
        f32x4 acc = (f32x4)0.f;
        acc = __builtin_amdgcn_mfma_f32_16x16x32_bf16(A[os * 2].s, Bf0.s, acc, 0, 0, 0);
        acc = __builtin_amdgcn_mfma_f32_16x16x32_bf16(A[os * 2 + 1].s, Bf1.s, acc, 0, 0, 0);
        #pragma unroll
        for (int e = 0; e < 4; e++) om[os][e] = fmaxf(om[os][e], acc[e]);
      }
    }
  }

  // epilogue: D layout col=n (j), row=q*4+e (o)
  const int jgl = h0 + jl;
  #pragma unroll
  for (int os = 0; os < 4; os++) {
    #pragma unroll
    for (int e = 0; e < 4; e++) {
      const int o = os * 16 + q * 4 + e;
      const size_t idx = ((size_t)b * Cn + o) * HWn + (size_t)w * Hn + jgl;
      float v = om[os][e] + b2[o];
      if (add_res) v += xres[idx];
      out[idx] = v;
      if (partial) {
        float sv = v, s2v = v * v;
        #pragma unroll
        for (int mask = 1; mask <= 8; mask <<= 1) {
          sv  += __shfl_xor(sv, mask, 64);
          s2v += __shfl_xor(s2v, mask, 64);
        }
        if (n == 0) {
          const int g = os * 8 + q * 2 + (e >> 1);
          atomicAdd(&gsA[g], sv);
          atomicAdd(&gsB[g], s2v);
        }
      }
    }
  }
  if (partial) {
    __syncthreads();
    if (t < 32) {
      atomicAdd(&partial[(b * 32 + t) * 2], gsA[t]);
      atomicAdd(&partial[(b * 32 + t) * 2 + 1], gsB[t]);
    }
  }
}

}  // namespace

extern "C" void kernel_launch(void* const* d_in, const int* in_sizes, int n_in,
                              void* d_out, int out_size, void* d_ws, size_t ws_size,
                              hipStream_t stream) {
  const float* x    = (const float*)d_in[0];
  const float* r    = (const float*)d_in[1];
  const float* n1w  = (const float*)d_in[2];
  const float* n1b  = (const float*)d_in[3];
  const float* c1w1 = (const float*)d_in[4];
  const float* c1b1 = (const float*)d_in[5];
  const float* c1w2 = (const float*)d_in[6];
  const float* c1b2 = (const float*)d_in[7];
  const float* n2w  = (const float*)d_in[8];
  const float* n2b  = (const float*)d_in[9];
  const float* c2w1 = (const float*)d_in[10];
  const float* c2b1 = (const float*)d_in[11];
  const float* c2w2 = (const float*)d_in[12];
  const float* c2b2 = (const float*)d_in[13];
  float* out = (float*)d_out;

  // ws: [partial1 256f][partial2 256f][stats 256f][pad to 4096B][Y bf16 32MiB][Z bf16 32MiB]
  float* partial1 = (float*)d_ws;
  float* partial2 = partial1 + 256;
  float* statsf   = partial1 + 512;
  ushort* Ybf = (ushort*)((char*)d_ws + 4096);
  ushort* Zbf = Ybf + (size_t)Bn * Wn * Hn * 64;

  ShiftConsts sc;
  for (int s = 0; s < 9; s++) {
    const int sw = s / 3 - 1, sh = s % 3 - 1;
    const double ca = cos(sw * 0.006135923151542565);
    const double sa = sin(sw * 0.006135923151542565);
    const double ci = cos(sh * 0.008267349088394194);
    const double si = sin(sh * 0.008267349088394194);
    sc.m[s]      = (float)(ca * ci);
    sc.m[9 + s]  = (float)(ca * si);
    sc.m[18 + s] = (float)sa;
  }

  hipMemsetAsync(partial1, 0, 512 * sizeof(float), stream);
  // ---- block 1 ----
  gn_partial_kernel<<<2048, 256, 0, stream>>>(x, partial1);
  gn_final_kernel<<<1, 128, 0, stream>>>(partial1, statsf);
  dual_gemm_kernel<<<2048, 256, 0, stream>>>(x, statsf, n1w, n1b, c1w1, c1b1, Ybf, Zbf);
  shift_max_kernel<<<4096, 256, 0, stream>>>(Ybf, Zbf, r, c1w1, c1w2, c1b2, x, 0, out, sc, partial2);
  // ---- block 2 (gn stats fused into shift_max-1 epilogue) ----
  gn_final_kernel<<<1, 128, 0, stream>>>(partial2, statsf);
  dual_gemm_kernel<<<2048, 256, 0, stream>>>(out, statsf, n2w, n2b, c2w1, c2b1, Ybf, Zbf);
  shift_max_kernel<<<4096, 256, 0, stream>>>(Ybf, Zbf, r, c2w1, c2w2, c2b2, x, 1, out, sc, nullptr);
}